// Round 1
// baseline (2208.644 us; speedup 1.0000x reference)
//
#include <hip/hip_runtime.h>
#include <hip/hip_fp16.h>

#define NN 16
#define BB 16
#define TT 512
#define II 256
#define HH 512

typedef _Float16 half2_t __attribute__((ext_vector_type(2)));

#if defined(__has_builtin)
#  if __has_builtin(__builtin_amdgcn_fdot2)
#    define USE_FDOT2 1
#  endif
#endif

__device__ __forceinline__ float fdot2(half2_t a, half2_t b, float c) {
#ifdef USE_FDOT2
    return __builtin_amdgcn_fdot2(a, b, c, false);
#else
    return c + (float)a[0] * (float)b[0] + (float)a[1] * (float)b[1];
#endif
}

// ---------------------------------------------------------------------------
// Kernel 1: pre[n][bt][h] = sum_i x[n][bt][i] * w_ih[n][h][i] + b_ih[n][h] + b_hh[n][h]
// Tiled 64x64, K=256 staged in two 128-wide chunks of LDS (fp16), dot2 compute.
// ---------------------------------------------------------------------------
__global__ __launch_bounds__(256) void k1_xproj(
    const float* __restrict__ x,
    const float* __restrict__ w_ih,
    const float* __restrict__ b_ih,
    const float* __restrict__ b_hh,
    float* __restrict__ pre)
{
    __shared__ half2_t A2[64][65];   // +1 dword pad: conflict-free row access
    __shared__ half2_t B2[64][65];

    const int tid = threadIdx.x;
    const int n   = blockIdx.z;
    const int bt0 = blockIdx.x * 64;
    const int h0  = blockIdx.y * 64;

    const float* xa = x    + ((size_t)n * (BB * TT) + bt0) * II;
    const float* wb = w_ih + ((size_t)n * HH + h0) * II;

    const int tx = tid & 15;
    const int ty = tid >> 4;

    float acc[4][4] = {};

    for (int kc = 0; kc < 2; ++kc) {
        // stage 64 rows x 128 floats (32 float4 per row) of A and B, cvt to fp16
        #pragma unroll
        for (int rep = 0; rep < 8; ++rep) {
            int flat = rep * 256 + tid;        // 0..2047
            int row  = flat >> 5;
            int c4   = flat & 31;
            float4 v = reinterpret_cast<const float4*>(xa + (size_t)row * II + kc * 128)[c4];
            A2[row][c4 * 2]     = half2_t{(_Float16)v.x, (_Float16)v.y};
            A2[row][c4 * 2 + 1] = half2_t{(_Float16)v.z, (_Float16)v.w};
            float4 w = reinterpret_cast<const float4*>(wb + (size_t)row * II + kc * 128)[c4];
            B2[row][c4 * 2]     = half2_t{(_Float16)w.x, (_Float16)w.y};
            B2[row][c4 * 2 + 1] = half2_t{(_Float16)w.z, (_Float16)w.w};
        }
        __syncthreads();

        #pragma unroll
        for (int k2 = 0; k2 < 64; k2 += 2) {
            half2_t a0[4][2], b0[4][2];
            #pragma unroll
            for (int r = 0; r < 4; ++r) {
                a0[r][0] = A2[ty * 4 + r][k2];
                a0[r][1] = A2[ty * 4 + r][k2 + 1];
            }
            #pragma unroll
            for (int c = 0; c < 4; ++c) {
                b0[c][0] = B2[tx * 4 + c][k2];
                b0[c][1] = B2[tx * 4 + c][k2 + 1];
            }
            #pragma unroll
            for (int r = 0; r < 4; ++r)
                #pragma unroll
                for (int c = 0; c < 4; ++c)
                    acc[r][c] = fdot2(a0[r][1], b0[c][1],
                                fdot2(a0[r][0], b0[c][0], acc[r][c]));
        }
        __syncthreads();
    }

    float bias[4];
    #pragma unroll
    for (int c = 0; c < 4; ++c) {
        int h = h0 + tx * 4 + c;
        bias[c] = b_ih[n * HH + h] + b_hh[n * HH + h];
    }

    float* prow = pre + ((size_t)n * (BB * TT) + bt0) * HH + h0;
    #pragma unroll
    for (int r = 0; r < 4; ++r) {
        float4 ov;
        ov.x = acc[r][0] + bias[0];
        ov.y = acc[r][1] + bias[1];
        ov.z = acc[r][2] + bias[2];
        ov.w = acc[r][3] + bias[3];
        *reinterpret_cast<float4*>(prow + (size_t)(ty * 4 + r) * HH + tx * 4) = ov;
    }
}

// ---------------------------------------------------------------------------
// Kernel 2: persistent recurrence. One WG per (n,b) sequence, 1024 threads.
// Thread (o = tid&511, kh = tid>>9) holds w_hh[n][o][kh*256 .. +256) in 128
// half2 VGPRs. Per step: dot2 partials over LDS-resident h (broadcast reads),
// pair-reduce via LDS, tanh, in-place update of out[n][b][t][:].
// 86 KB dynamic LDS forces 1 WG/CU (exactly 256 CUs for 256 WGs).
// ---------------------------------------------------------------------------
#define K2_LDS 86016

__global__ __launch_bounds__(1024) void k2_rnn(
    const float* __restrict__ w_hh,
    float* __restrict__ out,     // [N][B][T][H]: holds pre on entry, h on exit
    float* __restrict__ hn)      // [N][B][H]
{
    extern __shared__ char smem[];
    _Float16* h1   = (_Float16*)smem;            // [512] current hidden, fp16
    float* partial = (float*)(smem + 2048);      // [1024]

    const int tid = threadIdx.x;
    const int o   = tid & (HH - 1);
    const int kh  = tid >> 9;
    const int n   = blockIdx.x >> 4;
    const int b   = blockIdx.x & 15;

    // Load this thread's half-row of w_hh into registers as packed fp16.
    const float* wrow = w_hh + ((size_t)(n * HH + o)) * HH + kh * (HH / 2);
    half2_t wr[128];
    #pragma unroll
    for (int j = 0; j < 64; ++j) {
        float4 v = reinterpret_cast<const float4*>(wrow)[j];
        wr[2 * j]     = half2_t{(_Float16)v.x, (_Float16)v.y};
        wr[2 * j + 1] = half2_t{(_Float16)v.z, (_Float16)v.w};
    }

    float* mybase = out + ((size_t)(n * BB + b)) * TT * HH + o;

    if (tid < HH) h1[tid] = (_Float16)0.f;
    float pre_next = 0.f;
    if (tid < HH) pre_next = mybase[0];
    __syncthreads();

    float hlast = 0.f;
    for (int t = 0; t < TT; ++t) {
        const uint4* hv = reinterpret_cast<const uint4*>(h1 + kh * (HH / 2));
        float acc0 = 0.f, acc1 = 0.f;
        #pragma unroll
        for (int j = 0; j < 32; ++j) {
            uint4 hq = hv[j];   // 8 halves; whole wave reads same addr (broadcast)
            acc0 = fdot2(wr[4 * j + 0], __builtin_bit_cast(half2_t, hq.x), acc0);
            acc1 = fdot2(wr[4 * j + 1], __builtin_bit_cast(half2_t, hq.y), acc1);
            acc0 = fdot2(wr[4 * j + 2], __builtin_bit_cast(half2_t, hq.z), acc0);
            acc1 = fdot2(wr[4 * j + 3], __builtin_bit_cast(half2_t, hq.w), acc1);
        }
        partial[tid] = acc0 + acc1;
        __syncthreads();
        if (tid < HH) {
            float s = pre_next + partial[tid] + partial[tid + HH];
            float e = __expf(2.0f * s);
            float v = (e - 1.0f) / (e + 1.0f);   // tanh(s)
            mybase[(size_t)t * HH] = v;           // overwrite pre[t] with h[t]
            h1[o] = (_Float16)v;
            hlast = v;
            if (t + 1 < TT) pre_next = mybase[(size_t)(t + 1) * HH];
        }
        __syncthreads();
    }

    if (tid < HH) hn[((size_t)(n * BB + b)) * HH + o] = hlast;
}

// ---------------------------------------------------------------------------
extern "C" void kernel_launch(void* const* d_in, const int* in_sizes, int n_in,
                              void* d_out, int out_size, void* d_ws, size_t ws_size,
                              hipStream_t stream) {
    const float* x    = (const float*)d_in[0];
    const float* w_ih = (const float*)d_in[1];
    const float* w_hh = (const float*)d_in[2];
    const float* b_ih = (const float*)d_in[3];
    const float* b_hh = (const float*)d_in[4];

    float* out = (float*)d_out;                       // [N][B][T][H]
    float* hn  = out + (size_t)NN * BB * TT * HH;     // [N][B][H] tail

    // Phase 1: pre-projection (+ both biases) into the output region.
    dim3 g1(128, 8, 16);   // bt-tiles, h-tiles, n
    hipLaunchKernelGGL(k1_xproj, g1, dim3(256), 0, stream, x, w_ih, b_ih, b_hh, out);

    // Phase 2: in-place recurrence. Request >80KB LDS to force 1 WG/CU.
    hipFuncSetAttribute(reinterpret_cast<const void*>(k2_rnn),
                        hipFuncAttributeMaxDynamicSharedMemorySize, K2_LDS);
    hipLaunchKernelGGL(k2_rnn, dim3(NN * BB), dim3(1024), K2_LDS, stream,
                       w_hh, out, hn);
}

// Round 2
// 1663.013 us; speedup vs baseline: 1.3281x; 1.3281x over previous
//
#include <hip/hip_runtime.h>
#include <hip/hip_fp16.h>

#define NN 16
#define BB 16
#define TT 512
#define II 256
#define HH 512

typedef _Float16 half2_t __attribute__((ext_vector_type(2)));

#if defined(__has_builtin)
#  if __has_builtin(__builtin_amdgcn_fdot2)
#    define USE_FDOT2 1
#  endif
#endif

__device__ __forceinline__ float fdot2(half2_t a, half2_t b, float c) {
#ifdef USE_FDOT2
    return __builtin_amdgcn_fdot2(a, b, c, false);
#else
    return c + (float)a[0] * (float)b[0] + (float)a[1] * (float)b[1];
#endif
}

__device__ __forceinline__ half2_t bch(unsigned u) {
    return __builtin_bit_cast(half2_t, u);
}

// ---------------------------------------------------------------------------
// Kernel 1: pre[n][bt][h] = sum_i x[n][bt][i]*w_ih[n][h][i] + b_ih[n][h] + b_hh[n][h]
// 128(bt) x 64(h) tile, 8x4 per thread, fp16 dot2 compute from LDS.
// ---------------------------------------------------------------------------
__global__ __launch_bounds__(256, 3) void k1_xproj(
    const float* __restrict__ x,
    const float* __restrict__ w_ih,
    const float* __restrict__ b_ih,
    const float* __restrict__ b_hh,
    float* __restrict__ pre)
{
    __shared__ half2_t A2[128][65];   // +1 half2 pad
    __shared__ half2_t B2[64][65];

    const int tid = threadIdx.x;
    const int n   = blockIdx.z;
    const int bt0 = blockIdx.x * 128;
    const int h0  = blockIdx.y * 64;

    const float* xa = x    + ((size_t)n * (BB * TT) + bt0) * II;
    const float* wb = w_ih + ((size_t)n * HH + h0) * II;

    const int tx = tid & 15;    // h   dim: 4 cols each
    const int ty = tid >> 4;    // bt  dim: 8 rows each

    float acc[8][4] = {};

    for (int kc = 0; kc < 2; ++kc) {
        #pragma unroll
        for (int rep = 0; rep < 16; ++rep) {        // A: 128 rows x 32 float4
            int flat = rep * 256 + tid;
            int row  = flat >> 5;
            int c4   = flat & 31;
            float4 v = reinterpret_cast<const float4*>(xa + (size_t)row * II + kc * 128)[c4];
            A2[row][c4 * 2]     = half2_t{(_Float16)v.x, (_Float16)v.y};
            A2[row][c4 * 2 + 1] = half2_t{(_Float16)v.z, (_Float16)v.w};
        }
        #pragma unroll
        for (int rep = 0; rep < 8; ++rep) {         // B: 64 rows x 32 float4
            int flat = rep * 256 + tid;
            int row  = flat >> 5;
            int c4   = flat & 31;
            float4 w = reinterpret_cast<const float4*>(wb + (size_t)row * II + kc * 128)[c4];
            B2[row][c4 * 2]     = half2_t{(_Float16)w.x, (_Float16)w.y};
            B2[row][c4 * 2 + 1] = half2_t{(_Float16)w.z, (_Float16)w.w};
        }
        __syncthreads();

        #pragma unroll
        for (int k2 = 0; k2 < 64; k2 += 2) {
            half2_t a0[8][2], b0[4][2];
            #pragma unroll
            for (int r = 0; r < 8; ++r) {
                a0[r][0] = A2[ty * 8 + r][k2];
                a0[r][1] = A2[ty * 8 + r][k2 + 1];
            }
            #pragma unroll
            for (int c = 0; c < 4; ++c) {
                b0[c][0] = B2[tx * 4 + c][k2];
                b0[c][1] = B2[tx * 4 + c][k2 + 1];
            }
            #pragma unroll
            for (int r = 0; r < 8; ++r)
                #pragma unroll
                for (int c = 0; c < 4; ++c)
                    acc[r][c] = fdot2(a0[r][1], b0[c][1],
                                fdot2(a0[r][0], b0[c][0], acc[r][c]));
        }
        __syncthreads();
    }

    float bias[4];
    #pragma unroll
    for (int c = 0; c < 4; ++c) {
        int h = h0 + tx * 4 + c;
        bias[c] = b_ih[n * HH + h] + b_hh[n * HH + h];
    }

    float* prow = pre + ((size_t)n * (BB * TT) + bt0) * HH + h0;
    #pragma unroll
    for (int r = 0; r < 8; ++r) {
        float4 ov;
        ov.x = acc[r][0] + bias[0];
        ov.y = acc[r][1] + bias[1];
        ov.z = acc[r][2] + bias[2];
        ov.w = acc[r][3] + bias[3];
        *reinterpret_cast<float4*>(prow + (size_t)(ty * 8 + r) * HH + tx * 4) = ov;
    }
}

// ---------------------------------------------------------------------------
// Kernel 2: persistent recurrence. One WG per (n,b), 1024 threads, 1 WG/CU.
// Thread (o=tid&511, kh=tid>>9) owns w_hh[n][o][kh*256..+256): 256 fp16 halves.
// Storage split to avoid spill at the 128-VGPR cap (4 waves/SIMD):
//   - halves [0,192): 96 half2 in VGPRs (wr[])
//   - halves [192,256): 32 half2 in LDS, interleaved [j][tid] uint2 layout
//     (8 B lane stride -> 2-way bank alias, free per m136)
// h broadcast via LDS (same-address b128 reads), pair K-reduce via LDS.
// ---------------------------------------------------------------------------
#define LREG 96
#define K2_LDS (1024 + 4096 + 16 * 1024 * 8)   // h1 + partial + wlds = 136192 B

__global__ __launch_bounds__(1024, 4) void k2_rnn(
    const float* __restrict__ w_hh,
    float* __restrict__ out,     // [N][B][T][H]: pre on entry, h on exit
    float* __restrict__ hn)      // [N][B][H]
{
    extern __shared__ char smem[];
    _Float16* h1   = (_Float16*)smem;                 // [512]
    float* partial = (float*)(smem + 1024);           // [1024]
    uint2* wlds    = (uint2*)(smem + 1024 + 4096);    // [16][1024]

    const int tid = threadIdx.x;
    const int o   = tid & (HH - 1);
    const int kh  = tid >> 9;
    const int n   = blockIdx.x >> 4;
    const int b   = blockIdx.x & 15;

    const float* wrow = w_hh + ((size_t)(n * HH + o)) * HH + kh * 256;

    // Register-resident weights: halves [0,192)
    half2_t wr[LREG];
    #pragma unroll
    for (int j = 0; j < 48; ++j) {
        float4 v = reinterpret_cast<const float4*>(wrow)[j];
        wr[2 * j]     = half2_t{(_Float16)v.x, (_Float16)v.y};
        wr[2 * j + 1] = half2_t{(_Float16)v.z, (_Float16)v.w};
    }
    // LDS-resident weights: halves [192,256) -> 16 uint2 per thread
    #pragma unroll
    for (int j = 0; j < 16; ++j) {
        float4 v = reinterpret_cast<const float4*>(wrow + 192)[j];
        uint2 u;
        u.x = __builtin_bit_cast(unsigned, half2_t{(_Float16)v.x, (_Float16)v.y});
        u.y = __builtin_bit_cast(unsigned, half2_t{(_Float16)v.z, (_Float16)v.w});
        wlds[j * 1024 + tid] = u;
    }

    float* mybase = out + ((size_t)(n * BB + b)) * TT * HH + o;

    if (tid < HH) h1[tid] = (_Float16)0.f;
    float pre_next = 0.f;
    if (tid < HH) pre_next = mybase[0];
    __syncthreads();

    float hlast = 0.f;
    for (int t = 0; t < TT; ++t) {
        const uint4* hv = reinterpret_cast<const uint4*>(h1 + kh * 256);
        float acc0 = 0.f, acc1 = 0.f;
        #pragma unroll
        for (int j = 0; j < 24; ++j) {              // register-weight part
            uint4 hq = hv[j];                       // broadcast read
            acc0 = fdot2(wr[4 * j + 0], bch(hq.x), acc0);
            acc1 = fdot2(wr[4 * j + 1], bch(hq.y), acc1);
            acc0 = fdot2(wr[4 * j + 2], bch(hq.z), acc0);
            acc1 = fdot2(wr[4 * j + 3], bch(hq.w), acc1);
        }
        #pragma unroll
        for (int j = 0; j < 8; ++j) {               // LDS-weight part
            uint4 hq = hv[24 + j];
            uint2 w0 = wlds[(2 * j) * 1024 + tid];
            uint2 w1 = wlds[(2 * j + 1) * 1024 + tid];
            acc0 = fdot2(bch(w0.x), bch(hq.x), acc0);
            acc1 = fdot2(bch(w0.y), bch(hq.y), acc1);
            acc0 = fdot2(bch(w1.x), bch(hq.z), acc0);
            acc1 = fdot2(bch(w1.y), bch(hq.w), acc1);
        }
        partial[tid] = acc0 + acc1;
        __syncthreads();
        if (tid < HH) {
            float s = pre_next + partial[tid] + partial[tid + HH];
            s = fminf(fmaxf(s, -15.f), 15.f);
            float e = __expf(2.0f * s);
            float v = (e - 1.0f) / (e + 1.0f);      // tanh(s)
            mybase[(size_t)t * HH] = v;             // overwrite pre[t] with h[t]
            h1[o] = (_Float16)v;
            hlast = v;
            if (t + 1 < TT) pre_next = mybase[(size_t)(t + 1) * HH];
        }
        __syncthreads();
    }

    if (tid < HH) hn[((size_t)(n * BB + b)) * HH + o] = hlast;
}

// ---------------------------------------------------------------------------
extern "C" void kernel_launch(void* const* d_in, const int* in_sizes, int n_in,
                              void* d_out, int out_size, void* d_ws, size_t ws_size,
                              hipStream_t stream) {
    const float* x    = (const float*)d_in[0];
    const float* w_ih = (const float*)d_in[1];
    const float* w_hh = (const float*)d_in[2];
    const float* b_ih = (const float*)d_in[3];
    const float* b_hh = (const float*)d_in[4];

    float* out = (float*)d_out;                       // [N][B][T][H]
    float* hn  = out + (size_t)NN * BB * TT * HH;     // [N][B][H] tail

    dim3 g1(64, 8, 16);   // bt-tiles(128), h-tiles(64), n
    hipLaunchKernelGGL(k1_xproj, g1, dim3(256), 0, stream, x, w_ih, b_ih, b_hh, out);

    hipFuncSetAttribute(reinterpret_cast<const void*>(k2_rnn),
                        hipFuncAttributeMaxDynamicSharedMemorySize, K2_LDS);
    hipLaunchKernelGGL(k2_rnn, dim3(NN * BB), dim3(1024), K2_LDS, stream,
                       w_hh, out, hn);
}